// Round 9
// baseline (244.181 us; speedup 1.0000x reference)
//
#include <hip/hip_runtime.h>
#include <hip/hip_bf16.h>
#include <hip/hip_fp16.h>

#define NFEAT 128
#define HID 16
#define NACT 18
#define NGRAPH 64
#define BSHIFT 7              // 128 nodes per bucket
#define BNODES 128
#define MAXBUCK 1024
#define CHUNK 6144            // edges per block in hist/scatter (stage fits 2 blocks/CU)
#define SORTCAP 5120          // max records per bucket (mean 4096, sigma 64: 16-sigma headroom)

// bucket histogram only (LDS-aggregated int atomics)
__global__ __launch_bounds__(256) void k_hist(int* __restrict__ bcnt,
                                              const int* __restrict__ dst,
                                              int E, int nbuck) {
    __shared__ int hist[MAXBUCK];
    int t = threadIdx.x;
    for (int i = t; i < nbuck; i += 256) hist[i] = 0;
    __syncthreads();
    int beg = blockIdx.x * CHUNK;
    int end = min(beg + CHUNK, E);
    int cnt = end - beg;
    int nvec = cnt & ~3;
    for (int i = t * 4; i < nvec; i += 1024) {
        int4 d4 = *reinterpret_cast<const int4*>(dst + beg + i);
        atomicAdd(&hist[d4.x >> BSHIFT], 1);
        atomicAdd(&hist[d4.y >> BSHIFT], 1);
        atomicAdd(&hist[d4.z >> BSHIFT], 1);
        atomicAdd(&hist[d4.w >> BSHIFT], 1);
    }
    for (int i = nvec + t; i < cnt; i += 256) atomicAdd(&hist[dst[beg + i] >> BSHIFT], 1);
    __syncthreads();
    for (int i = t; i < nbuck; i += 256) if (hist[i]) atomicAdd(&bcnt[i], hist[i]);
}

__global__ __launch_bounds__(1024) void k_scan(const int* __restrict__ bcnt,
                                               int* __restrict__ bptr,
                                               int* __restrict__ cursor,
                                               int* __restrict__ rowptr,
                                               int nbuck, int E, int N) {
    __shared__ int ts[1024];
    int t = threadIdx.x;
    int v = (t < nbuck) ? bcnt[t] : 0;
    ts[t] = v;
    __syncthreads();
    for (int off = 1; off < 1024; off <<= 1) {
        int tmp = (t >= off) ? ts[t - off] : 0;
        __syncthreads();
        ts[t] += tmp;
        __syncthreads();
    }
    if (t < nbuck) {
        int r = ts[t] - v;          // exclusive prefix
        bptr[t] = r;
        cursor[t] = r;
        if (t == nbuck - 1) bptr[nbuck] = E;
    }
    if (t == 0) rowptr[N] = E;
}

// staged, write-coalesced bucket scatter: record = (dstoff<<24 | src, raw_w)
__global__ __launch_bounds__(256) void k_bscatter(int2* __restrict__ edata,
                                                  int* __restrict__ cursor,
                                                  const int* __restrict__ src,
                                                  const int* __restrict__ dst,
                                                  const float* __restrict__ w,
                                                  int E, int nbuck) {
    __shared__ int2 stage[CHUNK];              // 48KB
    __shared__ unsigned short bkid[CHUNK];     // 12KB
    __shared__ int hist[MAXBUCK];              // doubles as placement cursor
    __shared__ int pfx[MAXBUCK];
    __shared__ int basev[MAXBUCK];
    __shared__ int ts[256];
    int t = threadIdx.x;
    int beg = blockIdx.x * CHUNK;
    int end = min(beg + CHUNK, E);
    int cnt = end - beg;
    int nvec = cnt & ~3;
    for (int i = t; i < MAXBUCK; i += 256) hist[i] = 0;
    __syncthreads();
    // pass 1: local bucket histogram
    for (int i = t * 4; i < nvec; i += 1024) {
        int4 d4 = *reinterpret_cast<const int4*>(dst + beg + i);
        atomicAdd(&hist[d4.x >> BSHIFT], 1);
        atomicAdd(&hist[d4.y >> BSHIFT], 1);
        atomicAdd(&hist[d4.z >> BSHIFT], 1);
        atomicAdd(&hist[d4.w >> BSHIFT], 1);
    }
    for (int i = nvec + t; i < cnt; i += 256) atomicAdd(&hist[dst[beg + i] >> BSHIFT], 1);
    __syncthreads();
    // scan 1024 bins, 4 per thread
    int b4 = t * 4;
    int h0 = hist[b4], h1 = hist[b4 + 1], h2 = hist[b4 + 2], h3 = hist[b4 + 3];
    int s = h0 + h1 + h2 + h3;
    ts[t] = s;
    __syncthreads();
    for (int off = 1; off < 256; off <<= 1) {
        int tmp = (t >= off) ? ts[t - off] : 0;
        __syncthreads();
        ts[t] += tmp;
        __syncthreads();
    }
    int run = ts[t] - s;
    pfx[b4] = run; run += h0;
    pfx[b4 + 1] = run; run += h1;
    pfx[b4 + 2] = run; run += h2;
    pfx[b4 + 3] = run;
    __syncthreads();
    // reserve global runs; then hist becomes the placement cursor (= pfx copy)
    for (int b = t; b < nbuck; b += 256) {
        int c = hist[b];
        if (c) basev[b] = atomicAdd(&cursor[b], c);
    }
    __syncthreads();
    for (int b = t; b < MAXBUCK; b += 256) hist[b] = pfx[b];
    __syncthreads();
    // pass 2: place records bucket-sorted into LDS stage
    for (int i = t * 4; i < nvec; i += 1024) {
        int4 s4 = *reinterpret_cast<const int4*>(src + beg + i);
        int4 d4 = *reinterpret_cast<const int4*>(dst + beg + i);
        float4 w4 = *reinterpret_cast<const float4*>(w + beg + i);
        int bk, pos;
        bk = d4.x >> BSHIFT; pos = atomicAdd(&hist[bk], 1);
        stage[pos] = make_int2(((d4.x & (BNODES - 1)) << 24) | s4.x, __float_as_int(w4.x)); bkid[pos] = (unsigned short)bk;
        bk = d4.y >> BSHIFT; pos = atomicAdd(&hist[bk], 1);
        stage[pos] = make_int2(((d4.y & (BNODES - 1)) << 24) | s4.y, __float_as_int(w4.y)); bkid[pos] = (unsigned short)bk;
        bk = d4.z >> BSHIFT; pos = atomicAdd(&hist[bk], 1);
        stage[pos] = make_int2(((d4.z & (BNODES - 1)) << 24) | s4.z, __float_as_int(w4.z)); bkid[pos] = (unsigned short)bk;
        bk = d4.w >> BSHIFT; pos = atomicAdd(&hist[bk], 1);
        stage[pos] = make_int2(((d4.w & (BNODES - 1)) << 24) | s4.w, __float_as_int(w4.w)); bkid[pos] = (unsigned short)bk;
    }
    for (int i = nvec + t; i < cnt; i += 256) {
        int d = dst[beg + i], sv = src[beg + i];
        int bk = d >> BSHIFT;
        int pos = atomicAdd(&hist[bk], 1);
        stage[pos] = make_int2(((d & (BNODES - 1)) << 24) | sv, __float_as_int(w[beg + i]));
        bkid[pos] = (unsigned short)bk;
    }
    __syncthreads();
    // write-out: linear over stage -> coalesced runs at reserved global offsets
    for (int i = t; i < cnt; i += 256) {
        int bk = bkid[i];
        edata[basev[bk] + (i - pfx[bk])] = stage[i];
    }
}

// per-bucket counting sort (LDS staging) + rowptr emission + weighted-degree -> dinv
__global__ __launch_bounds__(256) void k_bsort(int2* __restrict__ edata,
                                               const int* __restrict__ bptr,
                                               int* __restrict__ rowptr,
                                               float* __restrict__ dinv, int N) {
    __shared__ int2 stage[SORTCAP];
    __shared__ int hist[BNODES];
    __shared__ int cur[BNODES];
    __shared__ int ts[BNODES];
    __shared__ float wsum[BNODES];
    int t = threadIdx.x;
    int b = blockIdx.x;
    int beg = bptr[b], end = bptr[b + 1];
    int cnt = end - beg;
    if (t < BNODES) { hist[t] = 0; wsum[t] = 0.f; }
    __syncthreads();
    for (int i = t; i < cnt; i += 256) {
        int2 r = edata[beg + i];
        stage[i] = r;
        int doff = ((unsigned)r.x) >> 24;
        atomicAdd(&hist[doff], 1);
        atomicAdd(&wsum[doff], __int_as_float(r.y));
    }
    __syncthreads();
    if (t < BNODES) ts[t] = hist[t];
    __syncthreads();
    for (int off = 1; off < BNODES; off <<= 1) {
        int v = (t < BNODES && t >= off) ? ts[t - off] : 0;
        __syncthreads();
        if (t < BNODES) ts[t] += v;
        __syncthreads();
    }
    if (t < BNODES) {
        int excl = ts[t] - hist[t];
        cur[t] = excl;
        int n = b * BNODES + t;
        if (n < N) {
            rowptr[n] = beg + excl;
            dinv[n] = rsqrtf(1.0f + wsum[t]);   // self-loop weight 1 folded in
        }
    }
    __syncthreads();
    for (int i = t; i < cnt; i += 256) {
        int2 r = stage[i];
        int pos = atomicAdd(&cur[((unsigned)r.x) >> 24], 1);
        edata[beg + pos] = r;   // random within 32KB window: L2-resident
    }
}

// dense transform 1: hs = dinv .* (x @ W1), fp16 output, 16 nodes per block
__global__ __launch_bounds__(256) void k_gemm1(const float* __restrict__ x,
                                               const float* __restrict__ W1,
                                               const float* __restrict__ dinv,
                                               __half* __restrict__ hs) {
    __shared__ float xs[16 * 132];
    __shared__ float ws[NFEAT * HID];
    int t = threadIdx.x;
    for (int i = t; i < NFEAT * HID; i += 256) ws[i] = W1[i];
    const float* xblk = x + (size_t)blockIdx.x * 16 * NFEAT;
    #pragma unroll
    for (int rep = 0; rep < 2; rep++) {
        int i4 = (rep * 256 + t) * 4;
        int row = i4 >> 7, col = i4 & 127;
        float4 v = *reinterpret_cast<const float4*>(xblk + i4);
        *reinterpret_cast<float4*>(&xs[row * 132 + col]) = v;
    }
    __syncthreads();
    int r = t >> 4, j = t & 15;
    int n = blockIdx.x * 16 + r;
    float acc = 0.f;
    #pragma unroll
    for (int k = 0; k < NFEAT; k++) acc += xs[r * 132 + k] * ws[k * HID + j];
    hs[(size_t)n * HID + j] = __float2half(acc * dinv[n]);
}

// per-node register-gather SpMM on dinv-prescaled fp16 features:
//   acc[j] = sum_e w_e * hs[src_e][j];  pre = dv*(acc + hs[n][j]) + b[j]
// 8 nodes/block; per node: 32 lanes = 4 edge-slots x 8 j-pair lanes (half2).
// Unroll 8 with per-rec predication: a mean row (32 recs) is consumed in ONE
// block of 8 independent rec loads + 8 independent gathers -> ~2 serialized
// latencies per node instead of ~8-16.
// LAYER 1: hout = dinv .* (relu(pre) @ W2) (fp16)   LAYER 2: pooled = segment-max relu(pre)
template <int LAYER>
__global__ __launch_bounds__(256) void k_spmm(const __half* __restrict__ hin,
                                              const int2* __restrict__ edata,
                                              const int* __restrict__ rowptr,
                                              const float* __restrict__ dinv,
                                              const float* __restrict__ bias,
                                              const float* __restrict__ W2,
                                              __half* __restrict__ hout,
                                              const int* __restrict__ batch,
                                              unsigned* __restrict__ pooled,
                                              int N) {
    __shared__ float w2s[256];
    __shared__ float act[8][18];
    __shared__ unsigned pool[NGRAPH * HID];
    int t = threadIdx.x;
    if (LAYER == 1) w2s[t] = W2[t];
    if (LAYER == 2) {
        for (int i = t; i < NGRAPH * HID; i += 256) pool[i] = 0u;
        __syncthreads();
    }
    const __half2* hp = reinterpret_cast<const __half2*>(hin);
    int r = t >> 5;                 // node slot
    int sub = (t >> 3) & 3;         // edge slot
    int l8 = t & 7;                 // j-pair index
    int j0 = l8 * 2;
    int n = blockIdx.x * 8 + r;
    float a0 = 0.f, a1 = 0.f;
    if (n < N) {
        int beg = rowptr[n], end = rowptr[n + 1];
        const int2 z2 = make_int2(0, 0);
        for (int p0 = beg + sub; p0 < end; p0 += 32) {
            // 8 predicated independent rec loads (invalid -> w=0, src=0)
            int2 r0 = (p0      < end) ? edata[p0]      : z2;
            int2 r1 = (p0 + 4  < end) ? edata[p0 + 4]  : z2;
            int2 r2 = (p0 + 8  < end) ? edata[p0 + 8]  : z2;
            int2 r3 = (p0 + 12 < end) ? edata[p0 + 12] : z2;
            int2 r4 = (p0 + 16 < end) ? edata[p0 + 16] : z2;
            int2 r5 = (p0 + 20 < end) ? edata[p0 + 20] : z2;
            int2 r6 = (p0 + 24 < end) ? edata[p0 + 24] : z2;
            int2 r7 = (p0 + 28 < end) ? edata[p0 + 28] : z2;
            // 8 independent gathers (src 0 for invalid: contributes w=0)
            __half2 q0 = hp[(size_t)(r0.x & 0xFFFFFF) * 8 + l8];
            __half2 q1 = hp[(size_t)(r1.x & 0xFFFFFF) * 8 + l8];
            __half2 q2 = hp[(size_t)(r2.x & 0xFFFFFF) * 8 + l8];
            __half2 q3 = hp[(size_t)(r3.x & 0xFFFFFF) * 8 + l8];
            __half2 q4 = hp[(size_t)(r4.x & 0xFFFFFF) * 8 + l8];
            __half2 q5 = hp[(size_t)(r5.x & 0xFFFFFF) * 8 + l8];
            __half2 q6 = hp[(size_t)(r6.x & 0xFFFFFF) * 8 + l8];
            __half2 q7 = hp[(size_t)(r7.x & 0xFFFFFF) * 8 + l8];
            float2 f0 = __half22float2(q0), f1 = __half22float2(q1);
            float2 f2 = __half22float2(q2), f3 = __half22float2(q3);
            float2 f4 = __half22float2(q4), f5 = __half22float2(q5);
            float2 f6 = __half22float2(q6), f7 = __half22float2(q7);
            float w0 = __int_as_float(r0.y), w1 = __int_as_float(r1.y);
            float w2 = __int_as_float(r2.y), w3 = __int_as_float(r3.y);
            float w4 = __int_as_float(r4.y), w5 = __int_as_float(r5.y);
            float w6 = __int_as_float(r6.y), w7 = __int_as_float(r7.y);
            a0 += w0 * f0.x; a1 += w0 * f0.y;
            a0 += w1 * f1.x; a1 += w1 * f1.y;
            a0 += w2 * f2.x; a1 += w2 * f2.y;
            a0 += w3 * f3.x; a1 += w3 * f3.y;
            a0 += w4 * f4.x; a1 += w4 * f4.y;
            a0 += w5 * f5.x; a1 += w5 * f5.y;
            a0 += w6 * f6.x; a1 += w6 * f6.y;
            a0 += w7 * f7.x; a1 += w7 * f7.y;
        }
    }
    a0 += __shfl_xor(a0, 8, 32);  a1 += __shfl_xor(a1, 8, 32);
    a0 += __shfl_xor(a0, 16, 32); a1 += __shfl_xor(a1, 16, 32);
    float v0 = 0.f, v1 = 0.f;
    if (n < N) {
        float dv = dinv[n];
        float2 sf = __half22float2(hp[(size_t)n * 8 + l8]);
        v0 = dv * (a0 + sf.x) + bias[j0];
        v1 = dv * (a1 + sf.y) + bias[j0 + 1];
        v0 = v0 > 0.f ? v0 : 0.f;
        v1 = v1 > 0.f ? v1 : 0.f;
    }
    if (LAYER == 1) {
        if (sub == 0 && n < N) { act[r][j0] = v0; act[r][j0 + 1] = v1; }
        __syncthreads();
        int j = t & 15, hf = (t >> 4) & 1;
        if (hf == 0 && n < N) {
            float o = 0.f;
            #pragma unroll
            for (int k = 0; k < HID; ++k) o += act[r][k] * w2s[k * 16 + j];
            hout[(size_t)n * HID + j] = __float2half(o * dinv[n]);
        }
    } else {
        if (sub == 0 && n < N) {
            int g = batch[n];
            atomicMax(&pool[g * HID + j0], __float_as_uint(v0));
            atomicMax(&pool[g * HID + j0 + 1], __float_as_uint(v1));
        }
        __syncthreads();
        for (int i = t; i < NGRAPH * HID; i += 256) {
            unsigned u = pool[i];
            if (u) atomicMax(&pooled[i], u);
        }
    }
}

__global__ __launch_bounds__(256) void k_final(const unsigned* __restrict__ pooled,
                                               const float* __restrict__ Wl,
                                               const float* __restrict__ bl,
                                               float* __restrict__ out) {
    int gid = blockIdx.x * 256 + threadIdx.x;
    if (gid < NGRAPH * NACT) {
        int g = gid / NACT, a = gid - g * NACT;
        float acc = bl[a];
        #pragma unroll
        for (int k = 0; k < HID; k++)
            acc += __uint_as_float(pooled[g * HID + k]) * Wl[k * NACT + a];
        out[gid] = acc;
    }
}

extern "C" void kernel_launch(void* const* d_in, const int* in_sizes, int n_in,
                              void* d_out, int out_size, void* d_ws, size_t ws_size,
                              hipStream_t stream) {
    const float* x     = (const float*)d_in[0];
    const int*   ei    = (const int*)d_in[1];
    const float* ew    = (const float*)d_in[2];
    const int*   batch = (const int*)d_in[3];
    const float* W1    = (const float*)d_in[4];
    const float* b1    = (const float*)d_in[5];
    const float* W2    = (const float*)d_in[6];
    const float* b2    = (const float*)d_in[7];
    const float* Wl    = (const float*)d_in[8];
    const float* bl    = (const float*)d_in[9];
    float* out = (float*)d_out;

    int N = in_sizes[0] / NFEAT;
    int E = in_sizes[1] / 2;
    const int* srcIdx = ei;
    const int* dstIdx = ei + E;
    int nbuck = (N + BNODES - 1) >> BSHIFT;

    // workspace
    int2*   edata  = (int2*)d_ws;                       // [E]
    float*  dinv   = (float*)(edata + E);               // [N]
    __half* hs     = (__half*)(dinv + N);               // [N*HID] fp16, dinv-prescaled
    __half* hs2    = hs + (size_t)N * HID;              // [N*HID] fp16, dinv-prescaled
    int*    rowptr = (int*)(hs2 + (size_t)N * HID);     // [N+1]
    int*    bcnt   = rowptr + N + 1;                    // [MAXBUCK]
    int*    bptr   = bcnt + MAXBUCK;                    // [MAXBUCK+1]
    int*    cursor = bptr + MAXBUCK + 1;                // [MAXBUCK]
    unsigned* pooled = (unsigned*)(cursor + MAXBUCK);   // [NGRAPH*HID]

    int nbC = (E + CHUNK - 1) / CHUNK;

    hipMemsetAsync(bcnt, 0, MAXBUCK * sizeof(int), stream);
    hipMemsetAsync(pooled, 0, NGRAPH * HID * sizeof(unsigned), stream);

    k_hist    <<<nbC, 256, 0, stream>>>(bcnt, dstIdx, E, nbuck);
    k_scan    <<<1, 1024, 0, stream>>>(bcnt, bptr, cursor, rowptr, nbuck, E, N);
    k_bscatter<<<nbC, 256, 0, stream>>>(edata, cursor, srcIdx, dstIdx, ew, E, nbuck);
    k_bsort   <<<nbuck, 256, 0, stream>>>(edata, bptr, rowptr, dinv, N);

    k_gemm1   <<<N / 16, 256, 0, stream>>>(x, W1, dinv, hs);
    k_spmm<1> <<<(N + 7) / 8, 256, 0, stream>>>(hs, edata, rowptr, dinv, b1, W2, hs2, batch, pooled, N);
    k_spmm<2> <<<(N + 7) / 8, 256, 0, stream>>>(hs2, edata, rowptr, dinv, b2, nullptr, nullptr, batch, pooled, N);
    k_final   <<<(NGRAPH * NACT + 255) / 256, 256, 0, stream>>>(pooled, Wl, bl, out);
}

// Round 10
// 243.787 us; speedup vs baseline: 1.0016x; 1.0016x over previous
//
#include <hip/hip_runtime.h>
#include <hip/hip_bf16.h>
#include <hip/hip_fp16.h>

#define NFEAT 128
#define HID 16
#define NACT 18
#define NGRAPH 64
#define BSHIFT 7              // 128 nodes per bucket
#define BNODES 128
#define MAXBUCK 1024
#define CHUNK 6144            // edges per block in hist/scatter (stage fits 2 blocks/CU)
#define SORTCAP 5120          // max records per bucket (mean 4096, sigma 64: 16-sigma headroom)

// bucket histogram only (LDS-aggregated int atomics)
__global__ __launch_bounds__(256) void k_hist(int* __restrict__ bcnt,
                                              const int* __restrict__ dst,
                                              int E, int nbuck) {
    __shared__ int hist[MAXBUCK];
    int t = threadIdx.x;
    for (int i = t; i < nbuck; i += 256) hist[i] = 0;
    __syncthreads();
    int beg = blockIdx.x * CHUNK;
    int end = min(beg + CHUNK, E);
    int cnt = end - beg;
    int nvec = cnt & ~3;
    for (int i = t * 4; i < nvec; i += 1024) {
        int4 d4 = *reinterpret_cast<const int4*>(dst + beg + i);
        atomicAdd(&hist[d4.x >> BSHIFT], 1);
        atomicAdd(&hist[d4.y >> BSHIFT], 1);
        atomicAdd(&hist[d4.z >> BSHIFT], 1);
        atomicAdd(&hist[d4.w >> BSHIFT], 1);
    }
    for (int i = nvec + t; i < cnt; i += 256) atomicAdd(&hist[dst[beg + i] >> BSHIFT], 1);
    __syncthreads();
    for (int i = t; i < nbuck; i += 256) if (hist[i]) atomicAdd(&bcnt[i], hist[i]);
}

__global__ __launch_bounds__(1024) void k_scan(const int* __restrict__ bcnt,
                                               int* __restrict__ bptr,
                                               int* __restrict__ cursor,
                                               int* __restrict__ rowptr,
                                               int nbuck, int E, int N) {
    __shared__ int ts[1024];
    int t = threadIdx.x;
    int v = (t < nbuck) ? bcnt[t] : 0;
    ts[t] = v;
    __syncthreads();
    for (int off = 1; off < 1024; off <<= 1) {
        int tmp = (t >= off) ? ts[t - off] : 0;
        __syncthreads();
        ts[t] += tmp;
        __syncthreads();
    }
    if (t < nbuck) {
        int r = ts[t] - v;          // exclusive prefix
        bptr[t] = r;
        cursor[t] = r;
        if (t == nbuck - 1) bptr[nbuck] = E;
    }
    if (t == 0) rowptr[N] = E;
}

// staged, write-coalesced bucket scatter: record = (dstoff<<24 | src, raw_w)
__global__ __launch_bounds__(256) void k_bscatter(int2* __restrict__ edata,
                                                  int* __restrict__ cursor,
                                                  const int* __restrict__ src,
                                                  const int* __restrict__ dst,
                                                  const float* __restrict__ w,
                                                  int E, int nbuck) {
    __shared__ int2 stage[CHUNK];              // 48KB
    __shared__ unsigned short bkid[CHUNK];     // 12KB
    __shared__ int hist[MAXBUCK];              // doubles as placement cursor
    __shared__ int pfx[MAXBUCK];
    __shared__ int basev[MAXBUCK];
    __shared__ int ts[256];
    int t = threadIdx.x;
    int beg = blockIdx.x * CHUNK;
    int end = min(beg + CHUNK, E);
    int cnt = end - beg;
    int nvec = cnt & ~3;
    for (int i = t; i < MAXBUCK; i += 256) hist[i] = 0;
    __syncthreads();
    // pass 1: local bucket histogram
    for (int i = t * 4; i < nvec; i += 1024) {
        int4 d4 = *reinterpret_cast<const int4*>(dst + beg + i);
        atomicAdd(&hist[d4.x >> BSHIFT], 1);
        atomicAdd(&hist[d4.y >> BSHIFT], 1);
        atomicAdd(&hist[d4.z >> BSHIFT], 1);
        atomicAdd(&hist[d4.w >> BSHIFT], 1);
    }
    for (int i = nvec + t; i < cnt; i += 256) atomicAdd(&hist[dst[beg + i] >> BSHIFT], 1);
    __syncthreads();
    // scan 1024 bins, 4 per thread
    int b4 = t * 4;
    int h0 = hist[b4], h1 = hist[b4 + 1], h2 = hist[b4 + 2], h3 = hist[b4 + 3];
    int s = h0 + h1 + h2 + h3;
    ts[t] = s;
    __syncthreads();
    for (int off = 1; off < 256; off <<= 1) {
        int tmp = (t >= off) ? ts[t - off] : 0;
        __syncthreads();
        ts[t] += tmp;
        __syncthreads();
    }
    int run = ts[t] - s;
    pfx[b4] = run; run += h0;
    pfx[b4 + 1] = run; run += h1;
    pfx[b4 + 2] = run; run += h2;
    pfx[b4 + 3] = run;
    __syncthreads();
    // reserve global runs; then hist becomes the placement cursor (= pfx copy)
    for (int b = t; b < nbuck; b += 256) {
        int c = hist[b];
        if (c) basev[b] = atomicAdd(&cursor[b], c);
    }
    __syncthreads();
    for (int b = t; b < MAXBUCK; b += 256) hist[b] = pfx[b];
    __syncthreads();
    // pass 2: place records bucket-sorted into LDS stage
    for (int i = t * 4; i < nvec; i += 1024) {
        int4 s4 = *reinterpret_cast<const int4*>(src + beg + i);
        int4 d4 = *reinterpret_cast<const int4*>(dst + beg + i);
        float4 w4 = *reinterpret_cast<const float4*>(w + beg + i);
        int bk, pos;
        bk = d4.x >> BSHIFT; pos = atomicAdd(&hist[bk], 1);
        stage[pos] = make_int2(((d4.x & (BNODES - 1)) << 24) | s4.x, __float_as_int(w4.x)); bkid[pos] = (unsigned short)bk;
        bk = d4.y >> BSHIFT; pos = atomicAdd(&hist[bk], 1);
        stage[pos] = make_int2(((d4.y & (BNODES - 1)) << 24) | s4.y, __float_as_int(w4.y)); bkid[pos] = (unsigned short)bk;
        bk = d4.z >> BSHIFT; pos = atomicAdd(&hist[bk], 1);
        stage[pos] = make_int2(((d4.z & (BNODES - 1)) << 24) | s4.z, __float_as_int(w4.z)); bkid[pos] = (unsigned short)bk;
        bk = d4.w >> BSHIFT; pos = atomicAdd(&hist[bk], 1);
        stage[pos] = make_int2(((d4.w & (BNODES - 1)) << 24) | s4.w, __float_as_int(w4.w)); bkid[pos] = (unsigned short)bk;
    }
    for (int i = nvec + t; i < cnt; i += 256) {
        int d = dst[beg + i], sv = src[beg + i];
        int bk = d >> BSHIFT;
        int pos = atomicAdd(&hist[bk], 1);
        stage[pos] = make_int2(((d & (BNODES - 1)) << 24) | sv, __float_as_int(w[beg + i]));
        bkid[pos] = (unsigned short)bk;
    }
    __syncthreads();
    // write-out: linear over stage -> coalesced runs at reserved global offsets
    for (int i = t; i < cnt; i += 256) {
        int bk = bkid[i];
        edata[basev[bk] + (i - pfx[bk])] = stage[i];
    }
}

// per-bucket counting sort (LDS staging) + rowptr emission + weighted-degree -> dinv
__global__ __launch_bounds__(256) void k_bsort(int2* __restrict__ edata,
                                               const int* __restrict__ bptr,
                                               int* __restrict__ rowptr,
                                               float* __restrict__ dinv, int N) {
    __shared__ int2 stage[SORTCAP];
    __shared__ int hist[BNODES];
    __shared__ int cur[BNODES];
    __shared__ int ts[BNODES];
    __shared__ float wsum[BNODES];
    int t = threadIdx.x;
    int b = blockIdx.x;
    int beg = bptr[b], end = bptr[b + 1];
    int cnt = end - beg;
    if (t < BNODES) { hist[t] = 0; wsum[t] = 0.f; }
    __syncthreads();
    for (int i = t; i < cnt; i += 256) {
        int2 r = edata[beg + i];
        stage[i] = r;
        int doff = ((unsigned)r.x) >> 24;
        atomicAdd(&hist[doff], 1);
        atomicAdd(&wsum[doff], __int_as_float(r.y));
    }
    __syncthreads();
    if (t < BNODES) ts[t] = hist[t];
    __syncthreads();
    for (int off = 1; off < BNODES; off <<= 1) {
        int v = (t < BNODES && t >= off) ? ts[t - off] : 0;
        __syncthreads();
        if (t < BNODES) ts[t] += v;
        __syncthreads();
    }
    if (t < BNODES) {
        int excl = ts[t] - hist[t];
        cur[t] = excl;
        int n = b * BNODES + t;
        if (n < N) {
            rowptr[n] = beg + excl;
            dinv[n] = rsqrtf(1.0f + wsum[t]);   // self-loop weight 1 folded in
        }
    }
    __syncthreads();
    for (int i = t; i < cnt; i += 256) {
        int2 r = stage[i];
        int pos = atomicAdd(&cur[((unsigned)r.x) >> 24], 1);
        edata[beg + pos] = r;   // random within 32KB window: L2-resident
    }
}

// dense transform 1: hs = dinv .* (x @ W1), fp16 output, 16 nodes per block
__global__ __launch_bounds__(256) void k_gemm1(const float* __restrict__ x,
                                               const float* __restrict__ W1,
                                               const float* __restrict__ dinv,
                                               __half* __restrict__ hs) {
    __shared__ float xs[16 * 132];
    __shared__ float ws[NFEAT * HID];
    int t = threadIdx.x;
    for (int i = t; i < NFEAT * HID; i += 256) ws[i] = W1[i];
    const float* xblk = x + (size_t)blockIdx.x * 16 * NFEAT;
    #pragma unroll
    for (int rep = 0; rep < 2; rep++) {
        int i4 = (rep * 256 + t) * 4;
        int row = i4 >> 7, col = i4 & 127;
        float4 v = *reinterpret_cast<const float4*>(xblk + i4);
        *reinterpret_cast<float4*>(&xs[row * 132 + col]) = v;
    }
    __syncthreads();
    int r = t >> 4, j = t & 15;
    int n = blockIdx.x * 16 + r;
    float acc = 0.f;
    #pragma unroll
    for (int k = 0; k < NFEAT; k++) acc += xs[r * 132 + k] * ws[k * HID + j];
    hs[(size_t)n * HID + j] = __float2half(acc * dinv[n]);
}

// per-node register-gather SpMM on dinv-prescaled fp16 features:
//   acc[j] = sum_e w_e * hs[src_e][j];  pre = dv*(acc + hs[n][j]) + b[j]
// 8 nodes/block; per node: 32 lanes = 4 edge-slots x 8 j-pair lanes (half2).
// edata is read NON-TEMPORALLY (stream must not evict the L2-resident hs),
// and the 8-deep unroll uses clamped-address UNCONDITIONAL loads (no exec-mask
// diamonds) so the compiler can batch all 8 loads in flight.
// LAYER 1: hout = dinv .* (relu(pre) @ W2) (fp16)   LAYER 2: pooled = segment-max relu(pre)
template <int LAYER>
__global__ __launch_bounds__(256, 4) void k_spmm(const __half* __restrict__ hin,
                                                 const int2* __restrict__ edata,
                                                 const int* __restrict__ rowptr,
                                                 const float* __restrict__ dinv,
                                                 const float* __restrict__ bias,
                                                 const float* __restrict__ W2,
                                                 __half* __restrict__ hout,
                                                 const int* __restrict__ batch,
                                                 unsigned* __restrict__ pooled,
                                                 int N) {
    __shared__ float w2s[256];
    __shared__ float act[8][18];
    __shared__ unsigned pool[NGRAPH * HID];
    int t = threadIdx.x;
    if (LAYER == 1) w2s[t] = W2[t];
    if (LAYER == 2) {
        for (int i = t; i < NGRAPH * HID; i += 256) pool[i] = 0u;
        __syncthreads();
    }
    const __half2* hp = reinterpret_cast<const __half2*>(hin);
    const unsigned long long* ep = reinterpret_cast<const unsigned long long*>(edata);
    int r = t >> 5;                 // node slot
    int sub = (t >> 3) & 3;         // edge slot
    int l8 = t & 7;                 // j-pair index
    int j0 = l8 * 2;
    int n = blockIdx.x * 8 + r;
    float a0 = 0.f, a1 = 0.f;
    if (n < N) {
        int beg = rowptr[n], end = rowptr[n + 1];
        int last = end - 1;
        for (int p0 = beg + sub; p0 < end; p0 += 32) {
            // 8 unconditional non-temporal loads at clamped addresses
            unsigned long long u0 = __builtin_nontemporal_load(ep + p0);
            unsigned long long u1 = __builtin_nontemporal_load(ep + min(p0 + 4, last));
            unsigned long long u2 = __builtin_nontemporal_load(ep + min(p0 + 8, last));
            unsigned long long u3 = __builtin_nontemporal_load(ep + min(p0 + 12, last));
            unsigned long long u4 = __builtin_nontemporal_load(ep + min(p0 + 16, last));
            unsigned long long u5 = __builtin_nontemporal_load(ep + min(p0 + 20, last));
            unsigned long long u6 = __builtin_nontemporal_load(ep + min(p0 + 24, last));
            unsigned long long u7 = __builtin_nontemporal_load(ep + min(p0 + 28, last));
            // 8 independent gathers from L2-resident hs
            __half2 q0 = hp[(size_t)(u0 & 0xFFFFFF) * 8 + l8];
            __half2 q1 = hp[(size_t)(u1 & 0xFFFFFF) * 8 + l8];
            __half2 q2 = hp[(size_t)(u2 & 0xFFFFFF) * 8 + l8];
            __half2 q3 = hp[(size_t)(u3 & 0xFFFFFF) * 8 + l8];
            __half2 q4 = hp[(size_t)(u4 & 0xFFFFFF) * 8 + l8];
            __half2 q5 = hp[(size_t)(u5 & 0xFFFFFF) * 8 + l8];
            __half2 q6 = hp[(size_t)(u6 & 0xFFFFFF) * 8 + l8];
            __half2 q7 = hp[(size_t)(u7 & 0xFFFFFF) * 8 + l8];
            // weights (zeroed for OOB clamped slots)
            float w0 = __int_as_float((int)(u0 >> 32));
            float w1 = (p0 + 4  <= last) ? __int_as_float((int)(u1 >> 32)) : 0.f;
            float w2 = (p0 + 8  <= last) ? __int_as_float((int)(u2 >> 32)) : 0.f;
            float w3 = (p0 + 12 <= last) ? __int_as_float((int)(u3 >> 32)) : 0.f;
            float w4 = (p0 + 16 <= last) ? __int_as_float((int)(u4 >> 32)) : 0.f;
            float w5 = (p0 + 20 <= last) ? __int_as_float((int)(u5 >> 32)) : 0.f;
            float w6 = (p0 + 24 <= last) ? __int_as_float((int)(u6 >> 32)) : 0.f;
            float w7 = (p0 + 28 <= last) ? __int_as_float((int)(u7 >> 32)) : 0.f;
            float2 f0 = __half22float2(q0), f1 = __half22float2(q1);
            float2 f2 = __half22float2(q2), f3 = __half22float2(q3);
            float2 f4 = __half22float2(q4), f5 = __half22float2(q5);
            float2 f6 = __half22float2(q6), f7 = __half22float2(q7);
            a0 += w0 * f0.x; a1 += w0 * f0.y;
            a0 += w1 * f1.x; a1 += w1 * f1.y;
            a0 += w2 * f2.x; a1 += w2 * f2.y;
            a0 += w3 * f3.x; a1 += w3 * f3.y;
            a0 += w4 * f4.x; a1 += w4 * f4.y;
            a0 += w5 * f5.x; a1 += w5 * f5.y;
            a0 += w6 * f6.x; a1 += w6 * f6.y;
            a0 += w7 * f7.x; a1 += w7 * f7.y;
        }
    }
    a0 += __shfl_xor(a0, 8, 32);  a1 += __shfl_xor(a1, 8, 32);
    a0 += __shfl_xor(a0, 16, 32); a1 += __shfl_xor(a1, 16, 32);
    float v0 = 0.f, v1 = 0.f;
    if (n < N) {
        float dv = dinv[n];
        float2 sf = __half22float2(hp[(size_t)n * 8 + l8]);
        v0 = dv * (a0 + sf.x) + bias[j0];
        v1 = dv * (a1 + sf.y) + bias[j0 + 1];
        v0 = v0 > 0.f ? v0 : 0.f;
        v1 = v1 > 0.f ? v1 : 0.f;
    }
    if (LAYER == 1) {
        if (sub == 0 && n < N) { act[r][j0] = v0; act[r][j0 + 1] = v1; }
        __syncthreads();
        int j = t & 15, hf = (t >> 4) & 1;
        if (hf == 0 && n < N) {
            float o = 0.f;
            #pragma unroll
            for (int k = 0; k < HID; ++k) o += act[r][k] * w2s[k * 16 + j];
            hout[(size_t)n * HID + j] = __float2half(o * dinv[n]);
        }
    } else {
        if (sub == 0 && n < N) {
            int g = batch[n];
            atomicMax(&pool[g * HID + j0], __float_as_uint(v0));
            atomicMax(&pool[g * HID + j0 + 1], __float_as_uint(v1));
        }
        __syncthreads();
        for (int i = t; i < NGRAPH * HID; i += 256) {
            unsigned u = pool[i];
            if (u) atomicMax(&pooled[i], u);
        }
    }
}

__global__ __launch_bounds__(256) void k_final(const unsigned* __restrict__ pooled,
                                               const float* __restrict__ Wl,
                                               const float* __restrict__ bl,
                                               float* __restrict__ out) {
    int gid = blockIdx.x * 256 + threadIdx.x;
    if (gid < NGRAPH * NACT) {
        int g = gid / NACT, a = gid - g * NACT;
        float acc = bl[a];
        #pragma unroll
        for (int k = 0; k < HID; k++)
            acc += __uint_as_float(pooled[g * HID + k]) * Wl[k * NACT + a];
        out[gid] = acc;
    }
}

extern "C" void kernel_launch(void* const* d_in, const int* in_sizes, int n_in,
                              void* d_out, int out_size, void* d_ws, size_t ws_size,
                              hipStream_t stream) {
    const float* x     = (const float*)d_in[0];
    const int*   ei    = (const int*)d_in[1];
    const float* ew    = (const float*)d_in[2];
    const int*   batch = (const int*)d_in[3];
    const float* W1    = (const float*)d_in[4];
    const float* b1    = (const float*)d_in[5];
    const float* W2    = (const float*)d_in[6];
    const float* b2    = (const float*)d_in[7];
    const float* Wl    = (const float*)d_in[8];
    const float* bl    = (const float*)d_in[9];
    float* out = (float*)d_out;

    int N = in_sizes[0] / NFEAT;
    int E = in_sizes[1] / 2;
    const int* srcIdx = ei;
    const int* dstIdx = ei + E;
    int nbuck = (N + BNODES - 1) >> BSHIFT;

    // workspace
    int2*   edata  = (int2*)d_ws;                       // [E]
    float*  dinv   = (float*)(edata + E);               // [N]
    __half* hs     = (__half*)(dinv + N);               // [N*HID] fp16, dinv-prescaled
    __half* hs2    = hs + (size_t)N * HID;              // [N*HID] fp16, dinv-prescaled
    int*    rowptr = (int*)(hs2 + (size_t)N * HID);     // [N+1]
    int*    bcnt   = rowptr + N + 1;                    // [MAXBUCK]
    int*    bptr   = bcnt + MAXBUCK;                    // [MAXBUCK+1]
    int*    cursor = bptr + MAXBUCK + 1;                // [MAXBUCK]
    unsigned* pooled = (unsigned*)(cursor + MAXBUCK);   // [NGRAPH*HID]

    int nbC = (E + CHUNK - 1) / CHUNK;

    hipMemsetAsync(bcnt, 0, MAXBUCK * sizeof(int), stream);
    hipMemsetAsync(pooled, 0, NGRAPH * HID * sizeof(unsigned), stream);

    k_hist    <<<nbC, 256, 0, stream>>>(bcnt, dstIdx, E, nbuck);
    k_scan    <<<1, 1024, 0, stream>>>(bcnt, bptr, cursor, rowptr, nbuck, E, N);
    k_bscatter<<<nbC, 256, 0, stream>>>(edata, cursor, srcIdx, dstIdx, ew, E, nbuck);
    k_bsort   <<<nbuck, 256, 0, stream>>>(edata, bptr, rowptr, dinv, N);

    k_gemm1   <<<N / 16, 256, 0, stream>>>(x, W1, dinv, hs);
    k_spmm<1> <<<(N + 7) / 8, 256, 0, stream>>>(hs, edata, rowptr, dinv, b1, W2, hs2, batch, pooled, N);
    k_spmm<2> <<<(N + 7) / 8, 256, 0, stream>>>(hs2, edata, rowptr, dinv, b2, nullptr, nullptr, batch, pooled, N);
    k_final   <<<(NGRAPH * NACT + 255) / 256, 256, 0, stream>>>(pooled, Wl, bl, out);
}

// Round 11
// 237.528 us; speedup vs baseline: 1.0280x; 1.0263x over previous
//
#include <hip/hip_runtime.h>
#include <hip/hip_bf16.h>
#include <hip/hip_fp16.h>

#define NFEAT 128
#define HID 16
#define NACT 18
#define NGRAPH 64
#define BSHIFT 7              // 128 nodes per bucket
#define BNODES 128
#define MAXBUCK 1024
#define CHUNK 6144            // edges per block in hist/scatter (stage fits 2 blocks/CU)
#define SORTCAP 5120          // max records per bucket (mean 4096, sigma 64: 16-sigma headroom)

typedef unsigned long long ull;

// bucket histogram only (LDS-aggregated int atomics)
__global__ __launch_bounds__(256) void k_hist(int* __restrict__ bcnt,
                                              const int* __restrict__ dst,
                                              int E, int nbuck) {
    __shared__ int hist[MAXBUCK];
    int t = threadIdx.x;
    for (int i = t; i < nbuck; i += 256) hist[i] = 0;
    __syncthreads();
    int beg = blockIdx.x * CHUNK;
    int end = min(beg + CHUNK, E);
    int cnt = end - beg;
    int nvec = cnt & ~3;
    for (int i = t * 4; i < nvec; i += 1024) {
        int4 d4 = *reinterpret_cast<const int4*>(dst + beg + i);
        atomicAdd(&hist[d4.x >> BSHIFT], 1);
        atomicAdd(&hist[d4.y >> BSHIFT], 1);
        atomicAdd(&hist[d4.z >> BSHIFT], 1);
        atomicAdd(&hist[d4.w >> BSHIFT], 1);
    }
    for (int i = nvec + t; i < cnt; i += 256) atomicAdd(&hist[dst[beg + i] >> BSHIFT], 1);
    __syncthreads();
    for (int i = t; i < nbuck; i += 256) if (hist[i]) atomicAdd(&bcnt[i], hist[i]);
}

__global__ __launch_bounds__(1024) void k_scan(const int* __restrict__ bcnt,
                                               int* __restrict__ bptr,
                                               int* __restrict__ cursor,
                                               int* __restrict__ rowptr,
                                               int nbuck, int E, int N) {
    __shared__ int ts[1024];
    int t = threadIdx.x;
    int v = (t < nbuck) ? bcnt[t] : 0;
    ts[t] = v;
    __syncthreads();
    for (int off = 1; off < 1024; off <<= 1) {
        int tmp = (t >= off) ? ts[t - off] : 0;
        __syncthreads();
        ts[t] += tmp;
        __syncthreads();
    }
    if (t < nbuck) {
        int r = ts[t] - v;          // exclusive prefix
        bptr[t] = r;
        cursor[t] = r;
        if (t == nbuck - 1) bptr[nbuck] = E;
    }
    if (t == 0) rowptr[N] = E;
}

// staged, write-coalesced bucket scatter: record = (dstoff<<24 | src, raw_w)
__global__ __launch_bounds__(256) void k_bscatter(int2* __restrict__ edata,
                                                  int* __restrict__ cursor,
                                                  const int* __restrict__ src,
                                                  const int* __restrict__ dst,
                                                  const float* __restrict__ w,
                                                  int E, int nbuck) {
    __shared__ int2 stage[CHUNK];              // 48KB
    __shared__ unsigned short bkid[CHUNK];     // 12KB
    __shared__ int hist[MAXBUCK];              // doubles as placement cursor
    __shared__ int pfx[MAXBUCK];
    __shared__ int basev[MAXBUCK];
    __shared__ int ts[256];
    int t = threadIdx.x;
    int beg = blockIdx.x * CHUNK;
    int end = min(beg + CHUNK, E);
    int cnt = end - beg;
    int nvec = cnt & ~3;
    for (int i = t; i < MAXBUCK; i += 256) hist[i] = 0;
    __syncthreads();
    // pass 1: local bucket histogram
    for (int i = t * 4; i < nvec; i += 1024) {
        int4 d4 = *reinterpret_cast<const int4*>(dst + beg + i);
        atomicAdd(&hist[d4.x >> BSHIFT], 1);
        atomicAdd(&hist[d4.y >> BSHIFT], 1);
        atomicAdd(&hist[d4.z >> BSHIFT], 1);
        atomicAdd(&hist[d4.w >> BSHIFT], 1);
    }
    for (int i = nvec + t; i < cnt; i += 256) atomicAdd(&hist[dst[beg + i] >> BSHIFT], 1);
    __syncthreads();
    // scan 1024 bins, 4 per thread
    int b4 = t * 4;
    int h0 = hist[b4], h1 = hist[b4 + 1], h2 = hist[b4 + 2], h3 = hist[b4 + 3];
    int s = h0 + h1 + h2 + h3;
    ts[t] = s;
    __syncthreads();
    for (int off = 1; off < 256; off <<= 1) {
        int tmp = (t >= off) ? ts[t - off] : 0;
        __syncthreads();
        ts[t] += tmp;
        __syncthreads();
    }
    int run = ts[t] - s;
    pfx[b4] = run; run += h0;
    pfx[b4 + 1] = run; run += h1;
    pfx[b4 + 2] = run; run += h2;
    pfx[b4 + 3] = run;
    __syncthreads();
    // reserve global runs; then hist becomes the placement cursor (= pfx copy)
    for (int b = t; b < nbuck; b += 256) {
        int c = hist[b];
        if (c) basev[b] = atomicAdd(&cursor[b], c);
    }
    __syncthreads();
    for (int b = t; b < MAXBUCK; b += 256) hist[b] = pfx[b];
    __syncthreads();
    // pass 2: place records bucket-sorted into LDS stage
    for (int i = t * 4; i < nvec; i += 1024) {
        int4 s4 = *reinterpret_cast<const int4*>(src + beg + i);
        int4 d4 = *reinterpret_cast<const int4*>(dst + beg + i);
        float4 w4 = *reinterpret_cast<const float4*>(w + beg + i);
        int bk, pos;
        bk = d4.x >> BSHIFT; pos = atomicAdd(&hist[bk], 1);
        stage[pos] = make_int2(((d4.x & (BNODES - 1)) << 24) | s4.x, __float_as_int(w4.x)); bkid[pos] = (unsigned short)bk;
        bk = d4.y >> BSHIFT; pos = atomicAdd(&hist[bk], 1);
        stage[pos] = make_int2(((d4.y & (BNODES - 1)) << 24) | s4.y, __float_as_int(w4.y)); bkid[pos] = (unsigned short)bk;
        bk = d4.z >> BSHIFT; pos = atomicAdd(&hist[bk], 1);
        stage[pos] = make_int2(((d4.z & (BNODES - 1)) << 24) | s4.z, __float_as_int(w4.z)); bkid[pos] = (unsigned short)bk;
        bk = d4.w >> BSHIFT; pos = atomicAdd(&hist[bk], 1);
        stage[pos] = make_int2(((d4.w & (BNODES - 1)) << 24) | s4.w, __float_as_int(w4.w)); bkid[pos] = (unsigned short)bk;
    }
    for (int i = nvec + t; i < cnt; i += 256) {
        int d = dst[beg + i], sv = src[beg + i];
        int bk = d >> BSHIFT;
        int pos = atomicAdd(&hist[bk], 1);
        stage[pos] = make_int2(((d & (BNODES - 1)) << 24) | sv, __float_as_int(w[beg + i]));
        bkid[pos] = (unsigned short)bk;
    }
    __syncthreads();
    // write-out: linear over stage -> coalesced runs at reserved global offsets
    for (int i = t; i < cnt; i += 256) {
        int bk = bkid[i];
        edata[basev[bk] + (i - pfx[bk])] = stage[i];
    }
}

// per-bucket counting sort (LDS staging) + rowptr emission + weighted-degree -> dinv
__global__ __launch_bounds__(256) void k_bsort(int2* __restrict__ edata,
                                               const int* __restrict__ bptr,
                                               int* __restrict__ rowptr,
                                               float* __restrict__ dinv, int N) {
    __shared__ int2 stage[SORTCAP];
    __shared__ int hist[BNODES];
    __shared__ int cur[BNODES];
    __shared__ int ts[BNODES];
    __shared__ float wsum[BNODES];
    int t = threadIdx.x;
    int b = blockIdx.x;
    int beg = bptr[b], end = bptr[b + 1];
    int cnt = end - beg;
    if (t < BNODES) { hist[t] = 0; wsum[t] = 0.f; }
    __syncthreads();
    for (int i = t; i < cnt; i += 256) {
        int2 r = edata[beg + i];
        stage[i] = r;
        int doff = ((unsigned)r.x) >> 24;
        atomicAdd(&hist[doff], 1);
        atomicAdd(&wsum[doff], __int_as_float(r.y));
    }
    __syncthreads();
    if (t < BNODES) ts[t] = hist[t];
    __syncthreads();
    for (int off = 1; off < BNODES; off <<= 1) {
        int v = (t < BNODES && t >= off) ? ts[t - off] : 0;
        __syncthreads();
        if (t < BNODES) ts[t] += v;
        __syncthreads();
    }
    if (t < BNODES) {
        int excl = ts[t] - hist[t];
        cur[t] = excl;
        int n = b * BNODES + t;
        if (n < N) {
            rowptr[n] = beg + excl;
            dinv[n] = rsqrtf(1.0f + wsum[t]);   // self-loop weight 1 folded in
        }
    }
    __syncthreads();
    for (int i = t; i < cnt; i += 256) {
        int2 r = stage[i];
        int pos = atomicAdd(&cur[((unsigned)r.x) >> 24], 1);
        edata[beg + pos] = r;   // random within 32KB window: L2-resident
    }
}

// dense transform 1: hs = dinv .* (x @ W1), fp16 output, 16 nodes per block
__global__ __launch_bounds__(256) void k_gemm1(const float* __restrict__ x,
                                               const float* __restrict__ W1,
                                               const float* __restrict__ dinv,
                                               __half* __restrict__ hs) {
    __shared__ float xs[16 * 132];
    __shared__ float ws[NFEAT * HID];
    int t = threadIdx.x;
    for (int i = t; i < NFEAT * HID; i += 256) ws[i] = W1[i];
    const float* xblk = x + (size_t)blockIdx.x * 16 * NFEAT;
    #pragma unroll
    for (int rep = 0; rep < 2; rep++) {
        int i4 = (rep * 256 + t) * 4;
        int row = i4 >> 7, col = i4 & 127;
        float4 v = *reinterpret_cast<const float4*>(xblk + i4);
        *reinterpret_cast<float4*>(&xs[row * 132 + col]) = v;
    }
    __syncthreads();
    int r = t >> 4, j = t & 15;
    int n = blockIdx.x * 16 + r;
    float acc = 0.f;
    #pragma unroll
    for (int k = 0; k < NFEAT; k++) acc += xs[r * 132 + k] * ws[k * HID + j];
    hs[(size_t)n * HID + j] = __float2half(acc * dinv[n]);
}

// per-node register-gather SpMM on dinv-prescaled fp16 features.
// 8 nodes/block; per node: 32 lanes = 8 edge-slots x 4 j-quad lanes (half4/8B).
// Software-pipelined: prologue loads 4 recs/slot; each iter issues gathers for
// current recs, prefetches next 4 recs (hidden under gathers+FMA), then FMAs.
// 16 edges in flight per wave-instruction (2 nodes x 8 slots).
//   acc[j] = sum_e w_e * hs[src_e][j];  pre = dv*(acc + hs[n][j]) + b[j]
// LAYER 1: hout = dinv .* (relu(pre) @ W2) (fp16)   LAYER 2: pooled = segment-max relu(pre)
template <int LAYER>
__global__ __launch_bounds__(256, 4) void k_spmm(const __half* __restrict__ hin,
                                                 const int2* __restrict__ edata,
                                                 const int* __restrict__ rowptr,
                                                 const float* __restrict__ dinv,
                                                 const float* __restrict__ bias,
                                                 const float* __restrict__ W2,
                                                 __half* __restrict__ hout,
                                                 const int* __restrict__ batch,
                                                 unsigned* __restrict__ pooled,
                                                 int N) {
    __shared__ float w2s[256];
    __shared__ float act[8][20];
    __shared__ unsigned pool[NGRAPH * HID];
    int t = threadIdx.x;
    if (LAYER == 1) w2s[t] = W2[t];
    if (LAYER == 2) {
        for (int i = t; i < NGRAPH * HID; i += 256) pool[i] = 0u;
        __syncthreads();
    }
    const ull* hp4 = reinterpret_cast<const ull*>(hin);   // 8B = 4 halves
    const ull* ep  = reinterpret_cast<const ull*>(edata);
    int r = t >> 5;                 // node slot
    int sub = (t >> 2) & 7;         // edge slot 0..7
    int l4 = t & 3;                 // j-quad index
    int j0 = l4 * 4;
    int n = blockIdx.x * 8 + r;
    float a0 = 0.f, a1 = 0.f, a2 = 0.f, a3 = 0.f;
    if (n < N) {
        int beg = rowptr[n], end = rowptr[n + 1];
        if (beg < end) {
            int last = end - 1;
            int p = beg + sub;
            // prologue: 4 clamped rec loads per slot (stride 8)
            ull u0 = __builtin_nontemporal_load(ep + min(p,      last));
            ull u1 = __builtin_nontemporal_load(ep + min(p + 8,  last));
            ull u2 = __builtin_nontemporal_load(ep + min(p + 16, last));
            ull u3 = __builtin_nontemporal_load(ep + min(p + 24, last));
            while (p < end) {
                // gathers for current recs (32B rows, 4 lanes x 8B)
                ull q0 = hp4[(size_t)(u0 & 0xFFFFFF) * 4 + l4];
                ull q1 = hp4[(size_t)(u1 & 0xFFFFFF) * 4 + l4];
                ull q2 = hp4[(size_t)(u2 & 0xFFFFFF) * 4 + l4];
                ull q3 = hp4[(size_t)(u3 & 0xFFFFFF) * 4 + l4];
                // prefetch next iteration's recs (hidden under gathers+FMA)
                int np = p + 32;
                ull v0n = __builtin_nontemporal_load(ep + min(np,      last));
                ull v1n = __builtin_nontemporal_load(ep + min(np + 8,  last));
                ull v2n = __builtin_nontemporal_load(ep + min(np + 16, last));
                ull v3n = __builtin_nontemporal_load(ep + min(np + 24, last));
                // weights (zero for clamped OOB slots; p<=last always in-loop)
                float w0 = __int_as_float((int)(u0 >> 32));
                float w1 = (p + 8  <= last) ? __int_as_float((int)(u1 >> 32)) : 0.f;
                float w2 = (p + 16 <= last) ? __int_as_float((int)(u2 >> 32)) : 0.f;
                float w3 = (p + 24 <= last) ? __int_as_float((int)(u3 >> 32)) : 0.f;
                // unpack + FMA
                {
                    unsigned lo = (unsigned)q0, hi = (unsigned)(q0 >> 32);
                    float2 fl = __half22float2(*reinterpret_cast<__half2*>(&lo));
                    float2 fh = __half22float2(*reinterpret_cast<__half2*>(&hi));
                    a0 += w0 * fl.x; a1 += w0 * fl.y; a2 += w0 * fh.x; a3 += w0 * fh.y;
                }
                {
                    unsigned lo = (unsigned)q1, hi = (unsigned)(q1 >> 32);
                    float2 fl = __half22float2(*reinterpret_cast<__half2*>(&lo));
                    float2 fh = __half22float2(*reinterpret_cast<__half2*>(&hi));
                    a0 += w1 * fl.x; a1 += w1 * fl.y; a2 += w1 * fh.x; a3 += w1 * fh.y;
                }
                {
                    unsigned lo = (unsigned)q2, hi = (unsigned)(q2 >> 32);
                    float2 fl = __half22float2(*reinterpret_cast<__half2*>(&lo));
                    float2 fh = __half22float2(*reinterpret_cast<__half2*>(&hi));
                    a0 += w2 * fl.x; a1 += w2 * fl.y; a2 += w2 * fh.x; a3 += w2 * fh.y;
                }
                {
                    unsigned lo = (unsigned)q3, hi = (unsigned)(q3 >> 32);
                    float2 fl = __half22float2(*reinterpret_cast<__half2*>(&lo));
                    float2 fh = __half22float2(*reinterpret_cast<__half2*>(&hi));
                    a0 += w3 * fl.x; a1 += w3 * fl.y; a2 += w3 * fh.x; a3 += w3 * fh.y;
                }
                u0 = v0n; u1 = v1n; u2 = v2n; u3 = v3n;
                p = np;
            }
        }
    }
    // reduce across the 8 edge slots (lane bits 2..4)
    a0 += __shfl_xor(a0, 4);  a1 += __shfl_xor(a1, 4);  a2 += __shfl_xor(a2, 4);  a3 += __shfl_xor(a3, 4);
    a0 += __shfl_xor(a0, 8);  a1 += __shfl_xor(a1, 8);  a2 += __shfl_xor(a2, 8);  a3 += __shfl_xor(a3, 8);
    a0 += __shfl_xor(a0, 16); a1 += __shfl_xor(a1, 16); a2 += __shfl_xor(a2, 16); a3 += __shfl_xor(a3, 16);
    float v0 = 0.f, v1 = 0.f, v2 = 0.f, v3 = 0.f;
    if (n < N) {
        float dv = dinv[n];
        ull sq = hp4[(size_t)n * 4 + l4];
        unsigned lo = (unsigned)sq, hi = (unsigned)(sq >> 32);
        float2 sl = __half22float2(*reinterpret_cast<__half2*>(&lo));
        float2 sh = __half22float2(*reinterpret_cast<__half2*>(&hi));
        v0 = dv * (a0 + sl.x) + bias[j0];
        v1 = dv * (a1 + sl.y) + bias[j0 + 1];
        v2 = dv * (a2 + sh.x) + bias[j0 + 2];
        v3 = dv * (a3 + sh.y) + bias[j0 + 3];
        v0 = v0 > 0.f ? v0 : 0.f;
        v1 = v1 > 0.f ? v1 : 0.f;
        v2 = v2 > 0.f ? v2 : 0.f;
        v3 = v3 > 0.f ? v3 : 0.f;
    }
    if (LAYER == 1) {
        if (sub == 0 && n < N) {
            act[r][j0] = v0; act[r][j0 + 1] = v1; act[r][j0 + 2] = v2; act[r][j0 + 3] = v3;
        }
        __syncthreads();
        int j = t & 15, hf = (t >> 4) & 1;
        if (hf == 0 && n < N) {
            float o = 0.f;
            #pragma unroll
            for (int k = 0; k < HID; ++k) o += act[r][k] * w2s[k * 16 + j];
            hout[(size_t)n * HID + j] = __float2half(o * dinv[n]);
        }
    } else {
        if (sub == 0 && n < N) {
            int g = batch[n];
            atomicMax(&pool[g * HID + j0],     __float_as_uint(v0));
            atomicMax(&pool[g * HID + j0 + 1], __float_as_uint(v1));
            atomicMax(&pool[g * HID + j0 + 2], __float_as_uint(v2));
            atomicMax(&pool[g * HID + j0 + 3], __float_as_uint(v3));
        }
        __syncthreads();
        for (int i = t; i < NGRAPH * HID; i += 256) {
            unsigned u = pool[i];
            if (u) atomicMax(&pooled[i], u);
        }
    }
}

__global__ __launch_bounds__(256) void k_final(const unsigned* __restrict__ pooled,
                                               const float* __restrict__ Wl,
                                               const float* __restrict__ bl,
                                               float* __restrict__ out) {
    int gid = blockIdx.x * 256 + threadIdx.x;
    if (gid < NGRAPH * NACT) {
        int g = gid / NACT, a = gid - g * NACT;
        float acc = bl[a];
        #pragma unroll
        for (int k = 0; k < HID; k++)
            acc += __uint_as_float(pooled[g * HID + k]) * Wl[k * NACT + a];
        out[gid] = acc;
    }
}

extern "C" void kernel_launch(void* const* d_in, const int* in_sizes, int n_in,
                              void* d_out, int out_size, void* d_ws, size_t ws_size,
                              hipStream_t stream) {
    const float* x     = (const float*)d_in[0];
    const int*   ei    = (const int*)d_in[1];
    const float* ew    = (const float*)d_in[2];
    const int*   batch = (const int*)d_in[3];
    const float* W1    = (const float*)d_in[4];
    const float* b1    = (const float*)d_in[5];
    const float* W2    = (const float*)d_in[6];
    const float* b2    = (const float*)d_in[7];
    const float* Wl    = (const float*)d_in[8];
    const float* bl    = (const float*)d_in[9];
    float* out = (float*)d_out;

    int N = in_sizes[0] / NFEAT;
    int E = in_sizes[1] / 2;
    const int* srcIdx = ei;
    const int* dstIdx = ei + E;
    int nbuck = (N + BNODES - 1) >> BSHIFT;

    // workspace
    int2*   edata  = (int2*)d_ws;                       // [E]
    float*  dinv   = (float*)(edata + E);               // [N]
    __half* hs     = (__half*)(dinv + N);               // [N*HID] fp16, dinv-prescaled
    __half* hs2    = hs + (size_t)N * HID;              // [N*HID] fp16, dinv-prescaled
    int*    rowptr = (int*)(hs2 + (size_t)N * HID);     // [N+1]
    int*    bcnt   = rowptr + N + 1;                    // [MAXBUCK]
    int*    bptr   = bcnt + MAXBUCK;                    // [MAXBUCK+1]
    int*    cursor = bptr + MAXBUCK + 1;                // [MAXBUCK]
    unsigned* pooled = (unsigned*)(cursor + MAXBUCK);   // [NGRAPH*HID]

    int nbC = (E + CHUNK - 1) / CHUNK;

    hipMemsetAsync(bcnt, 0, MAXBUCK * sizeof(int), stream);
    hipMemsetAsync(pooled, 0, NGRAPH * HID * sizeof(unsigned), stream);

    k_hist    <<<nbC, 256, 0, stream>>>(bcnt, dstIdx, E, nbuck);
    k_scan    <<<1, 1024, 0, stream>>>(bcnt, bptr, cursor, rowptr, nbuck, E, N);
    k_bscatter<<<nbC, 256, 0, stream>>>(edata, cursor, srcIdx, dstIdx, ew, E, nbuck);
    k_bsort   <<<nbuck, 256, 0, stream>>>(edata, bptr, rowptr, dinv, N);

    k_gemm1   <<<N / 16, 256, 0, stream>>>(x, W1, dinv, hs);
    k_spmm<1> <<<(N + 7) / 8, 256, 0, stream>>>(hs, edata, rowptr, dinv, b1, W2, hs2, batch, pooled, N);
    k_spmm<2> <<<(N + 7) / 8, 256, 0, stream>>>(hs2, edata, rowptr, dinv, b2, nullptr, nullptr, batch, pooled, N);
    k_final   <<<(NGRAPH * NACT + 255) / 256, 256, 0, stream>>>(pooled, Wl, bl, out);
}